// Round 1
// baseline (293.405 us; speedup 1.0000x reference)
//
#include <hip/hip_runtime.h>

typedef unsigned short u16;
typedef unsigned int u32;
typedef __attribute__((ext_vector_type(8))) short short8;
typedef __attribute__((ext_vector_type(4))) float floatx4;

#define MDIM 4096
#define NDIM 4096
#define KDIM 4096
#define BM 256
#define BN 256
#define BK 64
#define LBUF 32768   // u16 per LDS double-buffer slot (64 KiB): A 2x8192 + B 2x8192

typedef const __attribute__((address_space(1))) void* gas_ptr;
typedef __attribute__((address_space(3))) void* lds_ptr;

// ---------------- fp32 -> bf16 conversion, both matrices, one launch --------
// Grid-stride, 32 B loads + 16 B stores per iteration (G11/G13).
__global__ __launch_bounds__(256) void cvt2_f32_bf16(const float* __restrict__ x,
                                                     const float* __restrict__ w,
                                                     u16* __restrict__ xa,
                                                     u16* __restrict__ wb) {
    const int half = (MDIM * KDIM) / 8;          // short8 units per matrix
    const int total = half * 2;
    const int stride = gridDim.x * blockDim.x;
    for (int i = blockIdx.x * blockDim.x + threadIdx.x; i < total; i += stride) {
        const float* src = x; u16* dst = xa; int off = i;
        if (i >= half) { src = w; dst = wb; off = i - half; }
        float4 f0 = ((const float4*)src)[off * 2];
        float4 f1 = ((const float4*)src)[off * 2 + 1];
#define RNE(v) ((short)(u16)(((v) + 0x7fffu + (((v) >> 16) & 1u)) >> 16))
        short8 o;
        o[0] = RNE(__float_as_uint(f0.x));
        o[1] = RNE(__float_as_uint(f0.y));
        o[2] = RNE(__float_as_uint(f0.z));
        o[3] = RNE(__float_as_uint(f0.w));
        o[4] = RNE(__float_as_uint(f1.x));
        o[5] = RNE(__float_as_uint(f1.y));
        o[6] = RNE(__float_as_uint(f1.z));
        o[7] = RNE(__float_as_uint(f1.w));
#undef RNE
        ((short8*)dst)[off] = o;
    }
}

// ---------------- bf16 GEMM, C = A * B^T + bias ----------------
// 256x256 tile, BK=64, 8 waves (2M x 4N), 128 KiB LDS, 8-phase counted-vmcnt
// schedule (T3+T4) with setprio around MFMA clusters (T5).
//
// LDS: per buffer (cur in {0,1}): Ah0, Ah1, Bh0, Bh1, each a [128][64] u16
// array (16 KiB) holding 256 rows x 32 k (two M-rows packed per LDS row).
// Element (r, kk) of half h lives at ldsrow = r>>1, chunk c = (r&1)*4 + kk/8,
// slot = c ^ (ldsrow&7)  -> u16 offset ldsrow*64 + slot*8 + (kk&7).
// The XOR spreads a fragment-read's 16 rows over all 8 slots (2 lanes/slot
// per 16-lane group = conflict-free, same property as the verified BK=64
// XOR-3 kernel that measured SQ_LDS_BANK_CONFLICT = 0).
//
// Staging: half-tile = 16 KiB = 512 threads x 2 x global_load_lds(16B), LDS
// destination linear in ci = l*512 + t; global source pre-swizzled so the
// linear write realizes the swizzled layout (m173 pattern).
//
// Schedule per K-tile t (buffer cur = t&1), 4 phases:
//  p1: read A(m0-3) + B(all) of h0 | stage T_{t+1}.A.h1 -> cur^1 | 16 MFMA
//  p2: read A(m4-7) of h0          | stage T_{t+1}.B.h1 -> cur^1 | 16 MFMA
//  p3: read A(m0-3) + B(all) of h1 | stage T_{t+2}.A.h0 -> cur   | 16 MFMA
//  p4: read A(m4-7) of h1          | stage T_{t+2}.B.h0 -> cur   | 16 MFMA
//      then s_waitcnt vmcnt(4): drains T_{t+1} completely, leaves the two
//      T_{t+2}.h0 half-tiles (4 loads) in flight across the barrier.
// h0 of cur is dead after p2's closing barrier, so p3/p4 may stage into it;
// h1 of cur^1 was last read two phases before p1's stage. No vmcnt(0) in the
// main loop. Prologue stages 6 half-tiles then vmcnt(4); epilogue drains 4->0.

__global__ __launch_bounds__(512, 2) void gemm_bt_bias(const u16* __restrict__ A,
                                                       const u16* __restrict__ B,
                                                       const float* __restrict__ bias,
                                                       float* __restrict__ C) {
    __shared__ u16 lds[2 * LBUF];   // 128 KiB

    const int t = threadIdx.x;
    const int bm0 = blockIdx.y * BM;
    const int bn0 = blockIdx.x * BN;

    const int wave = t >> 6;
    const int lane = t & 63;
    const int wmi = wave >> 2;          // 0..1  (M wave index, 128 rows each)
    const int wni = wave & 3;           // 0..3  (N wave index, 64 cols each)
    const int lr = lane & 15;           // fragment row within 16
    const int q  = lane >> 4;           // k-quad 0..3

    // staging source pointers: load l covers ci = l*512 + t
    const u16* gA[2]; const u16* gB[2];
#pragma unroll
    for (int l = 0; l < 2; ++l) {
        const int ci = l * 512 + t;
        const int ldsrow = ci >> 3;
        const int c = (ci & 7) ^ (ldsrow & 7);       // unswizzled chunk
        const int r = 2 * ldsrow + (c >> 2);         // tile row 0..255
        const int kk = (c & 3) * 8;                  // k offset within half
        gA[l] = A + (size_t)(bm0 + r) * KDIM + kk;
        gB[l] = B + (size_t)(bn0 + r) * KDIM + kk;
    }

    // fragment-read lane constants (slot is frag-index independent)
    const int aslot = (((lr & 1) << 2) + q) ^ ((lr >> 1) & 7);
    const int aLane = (wmi * 64 + (lr >> 1)) * 64 + aslot * 8;   // + i*512
    const int bLane = (wni * 32 + (lr >> 1)) * 64 + aslot * 8;   // + j*512

    floatx4 acc[8][4] = {};
    short8 af[4], bf[4];

#define STAGE_A(CUR, H, KT) do { \
    __builtin_amdgcn_global_load_lds((gas_ptr)(gA[0] + (KT) * BK + (H) * 32), \
        (lds_ptr)(lds + (CUR) * LBUF + (H) * 8192 + t * 8), 16, 0, 0); \
    __builtin_amdgcn_global_load_lds((gas_ptr)(gA[1] + (KT) * BK + (H) * 32), \
        (lds_ptr)(lds + (CUR) * LBUF + (H) * 8192 + 4096 + t * 8), 16, 0, 0); \
} while (0)

#define STAGE_B(CUR, H, KT) do { \
    __builtin_amdgcn_global_load_lds((gas_ptr)(gB[0] + (KT) * BK + (H) * 32), \
        (lds_ptr)(lds + (CUR) * LBUF + 16384 + (H) * 8192 + t * 8), 16, 0, 0); \
    __builtin_amdgcn_global_load_lds((gas_ptr)(gB[1] + (KT) * BK + (H) * 32), \
        (lds_ptr)(lds + (CUR) * LBUF + 16384 + (H) * 8192 + 4096 + t * 8), 16, 0, 0); \
} while (0)

#define LOAD_AF(CUR, H, I0) do { \
    const u16* _p = lds + (CUR) * LBUF + (H) * 8192 + aLane; \
    af[0] = *(const short8*)(_p + ((I0) + 0) * 512); \
    af[1] = *(const short8*)(_p + ((I0) + 1) * 512); \
    af[2] = *(const short8*)(_p + ((I0) + 2) * 512); \
    af[3] = *(const short8*)(_p + ((I0) + 3) * 512); \
} while (0)

#define LOAD_BF(CUR, H) do { \
    const u16* _q = lds + (CUR) * LBUF + 16384 + (H) * 8192 + bLane; \
    bf[0] = *(const short8*)(_q + 0 * 512); \
    bf[1] = *(const short8*)(_q + 1 * 512); \
    bf[2] = *(const short8*)(_q + 2 * 512); \
    bf[3] = *(const short8*)(_q + 3 * 512); \
} while (0)

#define MFMA_HALF(F) do { \
    _Pragma("unroll") \
    for (int i2 = 0; i2 < 4; ++i2) { \
        _Pragma("unroll") \
        for (int j = 0; j < 4; ++j) \
            acc[(F) * 4 + i2][j] = __builtin_amdgcn_mfma_f32_16x16x32_bf16( \
                af[i2], bf[j], acc[(F) * 4 + i2][j], 0, 0, 0); \
    } \
} while (0)

#define BAR() __builtin_amdgcn_s_barrier()
#define SB()  __builtin_amdgcn_sched_barrier(0)
#define WAIT_LGKM0() do { asm volatile("s_waitcnt lgkmcnt(0)" ::: "memory"); SB(); } while (0)
#define WAIT_VM4() asm volatile("s_waitcnt vmcnt(4)" ::: "memory")
#define WAIT_VM0() asm volatile("s_waitcnt vmcnt(0)" ::: "memory")

#define PHASE(DS, STG, F, TAILVM) do { \
    DS; \
    STG; \
    BAR(); \
    WAIT_LGKM0(); \
    __builtin_amdgcn_s_setprio(1); \
    MFMA_HALF(F); \
    __builtin_amdgcn_s_setprio(0); \
    TAILVM; \
    SB(); \
    BAR(); \
} while (0)

// one K-tile: DO_S12 / DO_S34 are compile-time 0/1 stage enables
#define KTILE(CUR, KT, DO_S12, DO_S34, TAILVM) do { \
    PHASE({ LOAD_AF(CUR, 0, 0); LOAD_BF(CUR, 0); }, \
          { if (DO_S12) STAGE_A((CUR) ^ 1, 1, (KT) + 1); }, 0, ((void)0)); \
    PHASE({ LOAD_AF(CUR, 0, 4); }, \
          { if (DO_S12) STAGE_B((CUR) ^ 1, 1, (KT) + 1); }, 1, ((void)0)); \
    PHASE({ LOAD_AF(CUR, 1, 0); LOAD_BF(CUR, 1); }, \
          { if (DO_S34) STAGE_A((CUR), 0, (KT) + 2); }, 0, ((void)0)); \
    PHASE({ LOAD_AF(CUR, 1, 4); }, \
          { if (DO_S34) STAGE_B((CUR), 0, (KT) + 2); }, 1, TAILVM); \
} while (0)

    // ---- prologue: T0 fully + T1.h0; leave T1.h0 (4 loads) in flight ----
    STAGE_A(0, 0, 0); STAGE_B(0, 0, 0);
    STAGE_A(0, 1, 0); STAGE_B(0, 1, 0);
    STAGE_A(1, 0, 1); STAGE_B(1, 0, 1);
    WAIT_VM4();
    BAR();

    // ---- main loop: tiles 0..61 (buffer = kt&1, compile-time via 2x unroll)
    int kt = 0;
    for (int it = 0; it < 31; ++it) {
        KTILE(0, kt, 1, 1, WAIT_VM4());
        KTILE(1, kt + 1, 1, 1, WAIT_VM4());
        kt += 2;
    }
    // ---- tail: tile 62 stages T63.h1 then drains; tile 63 stages nothing
    KTILE(0, 62, 1, 0, WAIT_VM0());
    KTILE(1, 63, 0, 0, ((void)0));

    // ---- epilogue: C/D layout col=lane&15, row=(lane>>4)*4+qq [m89-verified]
#pragma unroll
    for (int j = 0; j < 4; ++j) {
        const int col = bn0 + wni * 64 + j * 16 + lr;
        const float bv = bias[col];
#pragma unroll
        for (int i = 0; i < 8; ++i) {
            const int row0 = bm0 + wmi * 128 + i * 16 + q * 4;
#pragma unroll
            for (int qq = 0; qq < 4; ++qq)
                C[(size_t)(row0 + qq) * NDIM + col] = acc[i][j][qq] + bv;
        }
    }

#undef STAGE_A
#undef STAGE_B
#undef LOAD_AF
#undef LOAD_BF
#undef MFMA_HALF
#undef BAR
#undef SB
#undef WAIT_LGKM0
#undef WAIT_VM4
#undef WAIT_VM0
#undef PHASE
#undef KTILE
}

extern "C" void kernel_launch(void* const* d_in, const int* in_sizes, int n_in,
                              void* d_out, int out_size, void* d_ws, size_t ws_size,
                              hipStream_t stream) {
    const float* x = (const float*)d_in[0];      // (4096, 4096) fp32
    const float* w = (const float*)d_in[1];      // (4096, 4096) fp32, OUT x IN
    const float* bias = (const float*)d_in[2];   // (4096,) fp32
    float* out = (float*)d_out;                  // (4096, 4096) fp32

    u16* xa = (u16*)d_ws;                        // 32 MiB bf16 x
    u16* wb = xa + (size_t)MDIM * KDIM;          // 32 MiB bf16 W

    cvt2_f32_bf16<<<2048, 256, 0, stream>>>(x, w, xa, wb);

    dim3 grid(NDIM / BN, MDIM / BM);             // 16 x 16
    gemm_bt_bias<<<grid, dim3(512), 0, stream>>>(xa, wb, bias, out);
}

// Round 3
// 278.668 us; speedup vs baseline: 1.0529x; 1.0529x over previous
//
#include <hip/hip_runtime.h>

typedef unsigned short u16;
typedef unsigned int u32;
typedef __attribute__((ext_vector_type(8))) short short8;
typedef __attribute__((ext_vector_type(4))) float floatx4;

#define MDIM 4096
#define NDIM 4096
#define KDIM 4096
#define BM 256
#define BN 256
#define BK 64
#define LBUF 32768   // u16 per LDS double-buffer slot (64 KiB): A 2x8192 + B 2x8192

typedef const __attribute__((address_space(1))) void* gas_ptr;
typedef __attribute__((address_space(3))) void* lds_ptr;

// ---------------- fp32 -> bf16 conversion, both matrices, one launch --------
__global__ __launch_bounds__(256) void cvt2_f32_bf16(const float* __restrict__ x,
                                                     const float* __restrict__ w,
                                                     u16* __restrict__ xa,
                                                     u16* __restrict__ wb) {
    const int half = gridDim.x >> 1;
    int b = blockIdx.x;
    const float* src = x;
    u16* dst = xa;
    if (b >= half) { src = w; dst = wb; b -= half; }
    const int i = b * 256 + threadIdx.x;           // float4 index
    float4 f = ((const float4*)src)[i];
    u32 ua = __float_as_uint(f.x), ub = __float_as_uint(f.y);
    u32 uc = __float_as_uint(f.z), ud = __float_as_uint(f.w);
    ushort4 o;                                     // RNE to bf16
    o.x = (u16)((ua + 0x7fffu + ((ua >> 16) & 1u)) >> 16);
    o.y = (u16)((ub + 0x7fffu + ((ub >> 16) & 1u)) >> 16);
    o.z = (u16)((uc + 0x7fffu + ((uc >> 16) & 1u)) >> 16);
    o.w = (u16)((ud + 0x7fffu + ((ud >> 16) & 1u)) >> 16);
    ((ushort4*)dst)[i] = o;
}

// ---------------- bf16 GEMM, C = A * B^T + bias ----------------
// 256x256 tile, BK=64, 8 waves (2M x 4N), 128 KiB LDS.
// Register-lookahead schedule: each phase issues the NEXT phase's ds_reads
// (into the alternate af/bf register buffers), stages one half-tile part,
// then MFMAs on fragments read LAST phase. No lgkmcnt(0) drain before MFMA,
// ONE barrier per phase -> LDS pipe and matrix pipe overlap instead of
// alternating. Barriers are asm-volatile with "memory" clobber so the
// compiler cannot migrate ds_reads / global_load_lds across phase
// boundaries (raw __builtin s_barrier carries no memory semantics).
//
// LDS swizzle (verified, bank conflicts = 0): half-region =
// [128 ldsrows][8 slots][8 u16]; tile row r, k-chunk kk of half h lives at
// ldsrow = r>>1, chunk c = (r&1)*4 + kk/8, slot = c ^ (ldsrow&7). Staging
// realizes this with linear LDS writes + pre-swizzled global source (m173).
//
// Phase plan per tile T (buffer b = T&1), MFMA consumption order
// [h0.F0, h0.F1, h1.F0, h1.F1] (F0 = m0-3, F1 = m4-7, acc offsets 0/4):
//  p1: rd afB=h0.m4-7        | stage T+1.h1.A -> b^1 | MFMA(afA,bfA,0) | vmcnt(6) bar
//  p2: rd afA=h1.m0-3,bfB=h1 | stage T+1.h1.B -> b^1 | MFMA(afB,bfA,4) |          bar
//  p3: rd afB=h1.m4-7        | stage T+2.h0.A -> b   | MFMA(afA,bfB,0) | vmcnt(6) bar
//  p4: rd afA=T+1.h0.m0-3,   | stage T+2.h0.B -> b   | MFMA(afB,bfB,4) |          bar
//        bfA=T+1.h0 (b^1)
// Ledger (2 loads/stage): entering T.p1 outstanding = [T.h1.A/B, T+1.h0.A/B]
// (8). p1 +2 -> 10, vmcnt(6) drains T.h1 (read at p2). p3 +2 -> 10, vmcnt(6)
// drains T+1.h0 (read at p4). Every region's stage issues >=2 barriers after
// its last read issue, and that read is register-consumed (lgkm-waited) one
// phase after issue -> no cross-wave WAR. Loads get 5-6 phases of flight ->
// vmcnt never stalls. Prologue: 12 loads, vmcnt(8). Tail: tile62
// vmcnt(6)/vmcnt(4) with h0-stages off; tile63 vmcnt(0), no stages/lookahead.

__global__ __launch_bounds__(512, 2) void gemm_bt_bias(const u16* __restrict__ A,
                                                       const u16* __restrict__ B,
                                                       const float* __restrict__ bias,
                                                       float* __restrict__ C) {
    __shared__ u16 lds[2 * LBUF];   // 128 KiB

    const int t = threadIdx.x;
    const int bm0 = blockIdx.y * BM;
    const int bn0 = blockIdx.x * BN;

    const int wave = t >> 6;
    const int lane = t & 63;
    const int wmi = wave >> 2;          // 0..1  (M wave index, 128 rows each)
    const int wni = wave & 3;           // 0..3  (N wave index, 64 cols each)
    const int lr = lane & 15;           // fragment row within 16
    const int q  = lane >> 4;           // k-quad 0..3

    // staging source pointers (pointer-bumped by BK per tile so the per-phase
    // global offsets fold into the load's immediate)
    const u16* gA[2]; const u16* gB[2];
#pragma unroll
    for (int l = 0; l < 2; ++l) {
        const int ci = l * 512 + t;
        const int ldsrow = ci >> 3;
        const int c = (ci & 7) ^ (ldsrow & 7);       // unswizzled chunk
        const int r = 2 * ldsrow + (c >> 2);         // tile row 0..255
        const int kk = (c & 3) * 8;                  // k offset within half
        gA[l] = A + (size_t)(bm0 + r) * KDIM + kk;
        gB[l] = B + (size_t)(bn0 + r) * KDIM + kk;
    }

    // fragment-read lane constants (slot is frag-index independent)
    const int aslot = (((lr & 1) << 2) + q) ^ ((lr >> 1) & 7);
    const int aLane = (wmi * 64 + (lr >> 1)) * 64 + aslot * 8;   // + i*512
    const int bLane = (wni * 32 + (lr >> 1)) * 64 + aslot * 8;   // + j*512

    floatx4 acc[8][4] = {};
    short8 afA[4], afB[4], bfA[4], bfB[4];

#define STAGE_A(CUR, H, DK) do { \
    __builtin_amdgcn_global_load_lds((gas_ptr)(gA[0] + (DK) * BK + (H) * 32), \
        (lds_ptr)(lds + (CUR) * LBUF + (H) * 8192 + t * 8), 16, 0, 0); \
    __builtin_amdgcn_global_load_lds((gas_ptr)(gA[1] + (DK) * BK + (H) * 32), \
        (lds_ptr)(lds + (CUR) * LBUF + (H) * 8192 + 4096 + t * 8), 16, 0, 0); \
} while (0)

#define STAGE_B(CUR, H, DK) do { \
    __builtin_amdgcn_global_load_lds((gas_ptr)(gB[0] + (DK) * BK + (H) * 32), \
        (lds_ptr)(lds + (CUR) * LBUF + 16384 + (H) * 8192 + t * 8), 16, 0, 0); \
    __builtin_amdgcn_global_load_lds((gas_ptr)(gB[1] + (DK) * BK + (H) * 32), \
        (lds_ptr)(lds + (CUR) * LBUF + 16384 + (H) * 8192 + 4096 + t * 8), 16, 0, 0); \
} while (0)

#define RD_AF(DST, CUR, H, I0) do { \
    const u16* _p = lds + (CUR) * LBUF + (H) * 8192 + aLane; \
    DST[0] = *(const short8*)(_p + ((I0) + 0) * 512); \
    DST[1] = *(const short8*)(_p + ((I0) + 1) * 512); \
    DST[2] = *(const short8*)(_p + ((I0) + 2) * 512); \
    DST[3] = *(const short8*)(_p + ((I0) + 3) * 512); \
} while (0)

#define RD_BF(DST, CUR, H) do { \
    const u16* _q = lds + (CUR) * LBUF + 16384 + (H) * 8192 + bLane; \
    DST[0] = *(const short8*)(_q + 0 * 512); \
    DST[1] = *(const short8*)(_q + 1 * 512); \
    DST[2] = *(const short8*)(_q + 2 * 512); \
    DST[3] = *(const short8*)(_q + 3 * 512); \
} while (0)

#define MFMA16(AF, BF, IOFF) do { \
    _Pragma("unroll") \
    for (int i2 = 0; i2 < 4; ++i2) { \
        _Pragma("unroll") \
        for (int j = 0; j < 4; ++j) \
            acc[(IOFF) + i2][j] = __builtin_amdgcn_mfma_f32_16x16x32_bf16( \
                AF[i2], BF[j], acc[(IOFF) + i2][j], 0, 0, 0); \
    } \
} while (0)

#define VM8 asm volatile("s_waitcnt vmcnt(8)" ::: "memory")
#define VM6 asm volatile("s_waitcnt vmcnt(6)" ::: "memory")
#define VM4 asm volatile("s_waitcnt vmcnt(4)" ::: "memory")
#define VM0 asm volatile("s_waitcnt vmcnt(0)" ::: "memory")
#define NOVM ((void)0)
#define BAR() asm volatile("s_barrier" ::: "memory")

#define PH(RD, STG, MF, TAIL) do { \
    RD; \
    STG; \
    __builtin_amdgcn_s_setprio(1); \
    MF; \
    __builtin_amdgcn_s_setprio(0); \
    TAIL; \
    BAR(); \
} while (0)

#define KTILE(CUR, S12, S34, VM1, VM3, P4RD) do { \
    PH(RD_AF(afB, CUR, 0, 4), \
       { if (S12) STAGE_A((CUR) ^ 1, 1, 1); }, MFMA16(afA, bfA, 0), VM1); \
    PH({ RD_AF(afA, CUR, 1, 0); RD_BF(bfB, CUR, 1); }, \
       { if (S12) STAGE_B((CUR) ^ 1, 1, 1); }, MFMA16(afB, bfA, 4), NOVM); \
    PH(RD_AF(afB, CUR, 1, 4), \
       { if (S34) STAGE_A(CUR, 0, 2); }, MFMA16(afA, bfB, 0), VM3); \
    PH({ if (P4RD) { RD_AF(afA, (CUR) ^ 1, 0, 0); RD_BF(bfA, (CUR) ^ 1, 0); } }, \
       { if (S34) STAGE_B(CUR, 0, 2); }, MFMA16(afB, bfB, 4), NOVM); \
    gA[0] += BK; gA[1] += BK; gB[0] += BK; gB[1] += BK; \
} while (0)

    // ---- prologue: T0.h0, T0.h1, T1.h0 (12 loads); drain T0.h0; pre-read
    // p1's fragments (h0.m0-3 + h0.bf)
    STAGE_A(0, 0, 0); STAGE_B(0, 0, 0);
    STAGE_A(0, 1, 0); STAGE_B(0, 1, 0);
    STAGE_A(1, 0, 1); STAGE_B(1, 0, 1);
    VM8;
    BAR();
    RD_AF(afA, 0, 0, 0);
    RD_BF(bfA, 0, 0);

    // ---- main loop: tiles 0..61 ----
    for (int it = 0; it < 31; ++it) {
        KTILE(0, 1, 1, VM6, VM6, 1);
        KTILE(1, 1, 1, VM6, VM6, 1);
    }
    // ---- tail: tile 62 (stages T63.h1 only), tile 63 (stages nothing) ----
    KTILE(0, 1, 0, VM6, VM4, 1);
    KTILE(1, 0, 0, VM0, NOVM, 0);

    // ---- epilogue: C/D layout col=lane&15, row=(lane>>4)*4+qq [m89-verified]
#pragma unroll
    for (int j = 0; j < 4; ++j) {
        const int col = bn0 + wni * 64 + j * 16 + lr;
        const float bv = bias[col];
#pragma unroll
        for (int i = 0; i < 8; ++i) {
            const int row0 = bm0 + wmi * 128 + i * 16 + q * 4;
#pragma unroll
            for (int qq = 0; qq < 4; ++qq)
                C[(size_t)(row0 + qq) * NDIM + col] = acc[i][j][qq] + bv;
        }
    }

#undef STAGE_A
#undef STAGE_B
#undef RD_AF
#undef RD_BF
#undef MFMA16
#undef VM8
#undef VM6
#undef VM4
#undef VM0
#undef NOVM
#undef BAR
#undef PH
#undef KTILE
}

extern "C" void kernel_launch(void* const* d_in, const int* in_sizes, int n_in,
                              void* d_out, int out_size, void* d_ws, size_t ws_size,
                              hipStream_t stream) {
    const float* x = (const float*)d_in[0];      // (4096, 4096) fp32
    const float* w = (const float*)d_in[1];      // (4096, 4096) fp32, OUT x IN
    const float* bias = (const float*)d_in[2];   // (4096,) fp32
    float* out = (float*)d_out;                  // (4096, 4096) fp32

    u16* xa = (u16*)d_ws;                        // 32 MiB bf16 x
    u16* wb = xa + (size_t)MDIM * KDIM;          // 32 MiB bf16 W

    const int blocks_per_mat = (MDIM * KDIM) / 4 / 256;   // 16384
    cvt2_f32_bf16<<<blocks_per_mat * 2, 256, 0, stream>>>(x, w, xa, wb);

    dim3 grid(NDIM / BN, MDIM / BM);             // 16 x 16
    gemm_bt_bias<<<grid, dim3(512), 0, stream>>>(xa, wb, bias, out);
}

// Round 4
// 272.027 us; speedup vs baseline: 1.0786x; 1.0244x over previous
//
#include <hip/hip_runtime.h>

typedef unsigned short u16;
typedef unsigned int u32;
typedef __attribute__((ext_vector_type(8))) short short8;
typedef __attribute__((ext_vector_type(4))) float floatx4;

#define MDIM 4096
#define NDIM 4096
#define KDIM 4096
#define BM 256
#define BN 256
#define BK 64
#define LBUF 32768   // u16 per LDS double-buffer slot (64 KiB): A 2x8192 + B 2x8192

typedef const __attribute__((address_space(1))) void* gas_ptr;
typedef __attribute__((address_space(3))) void* lds_ptr;

// ---------------- fp32 -> bf16 conversion, both matrices, one launch --------
__global__ __launch_bounds__(256) void cvt2_f32_bf16(const float* __restrict__ x,
                                                     const float* __restrict__ w,
                                                     u16* __restrict__ xa,
                                                     u16* __restrict__ wb) {
    const int half = gridDim.x >> 1;
    int b = blockIdx.x;
    const float* src = x;
    u16* dst = xa;
    if (b >= half) { src = w; dst = wb; b -= half; }
    const int i = b * 256 + threadIdx.x;           // float4 index
    float4 f = ((const float4*)src)[i];
    u32 ua = __float_as_uint(f.x), ub = __float_as_uint(f.y);
    u32 uc = __float_as_uint(f.z), ud = __float_as_uint(f.w);
    ushort4 o;                                     // RNE to bf16
    o.x = (u16)((ua + 0x7fffu + ((ua >> 16) & 1u)) >> 16);
    o.y = (u16)((ub + 0x7fffu + ((ub >> 16) & 1u)) >> 16);
    o.z = (u16)((uc + 0x7fffu + ((uc >> 16) & 1u)) >> 16);
    o.w = (u16)((ud + 0x7fffu + ((ud >> 16) & 1u)) >> 16);
    ((ushort4*)dst)[i] = o;
}

// ---------------- bf16 GEMM, C = A * B^T + bias ----------------
// 256x256 tile, BK=64, 8 waves (2M x 4N), 128 KiB LDS.
// Register-lookahead schedule: each phase issues the NEXT phase's ds_reads
// (into the alternate af/bf register buffers), stages one half-tile part,
// then MFMAs on fragments read LAST phase. ONE barrier per phase.
//
// FENCING (round-4 fix): barriers are raw __builtin_amdgcn_s_barrier() --
// NO "memory"-clobber asm. A "memory" asm is mayLoad/mayStore, which forces
// SIInsertWaitcnts to emit s_waitcnt vmcnt(0) lgkmcnt(0) before it: that
// silently re-introduced the per-phase drain (the ~900TF-ceiling mechanism)
// and was round 3's 52%-MfmaUtil limiter. Ordering is pinned instead with
// __builtin_amdgcn_sched_barrier(0) (zero emitted instructions) at every
// phase edge and around each counted s_waitcnt, so global_load_lds issues
// cannot migrate across a wait and change its count. ds_read->MFMA waits
// are left to the compiler's precise counted lgkmcnt insertion.
//
// LDS swizzle (verified, bank conflicts = 0): half-region =
// [128 ldsrows][8 slots][8 u16]; tile row r, k-chunk kk of half h lives at
// ldsrow = r>>1, chunk c = (r&1)*4 + kk/8, slot = c ^ (ldsrow&7). Staging
// realizes this with linear LDS writes + pre-swizzled global source (m173).
//
// Phase plan per tile T (buffer b = T&1), MFMA consumption order
// [h0.F0, h0.F1, h1.F0, h1.F1] (F0 = m0-3, F1 = m4-7, acc offsets 0/4):
//  p1: rd afB=h0.m4-7        | stage T+1.h1.A -> b^1 | MFMA(afA,bfA,0) | vmcnt(6) bar
//  p2: rd afA=h1.m0-3,bfB=h1 | stage T+1.h1.B -> b^1 | MFMA(afB,bfA,4) |          bar
//  p3: rd afB=h1.m4-7        | stage T+2.h0.A -> b   | MFMA(afA,bfB,0) | vmcnt(6) bar
//  p4: rd afA=T+1.h0.m0-3,   | stage T+2.h0.B -> b   | MFMA(afB,bfB,4) |          bar
//        bfA=T+1.h0 (b^1)
// Ledger (2 loads/stage): entering T.p1 outstanding = [T.h1.A/B, T+1.h0.A/B]
// (8). p1 +2 -> 10, vmcnt(6) drains T.h1 (read at p2). p3 +2 -> 10, vmcnt(6)
// drains T+1.h0 (read at p4). Every region's stage issues >=2 barriers after
// its last read issue, and that read is register-consumed one phase after
// issue -> no cross-wave WAR (even a read hoisted one barrier up only
// touches a region vmcnt-drained a phase earlier). Loads get 5-6 phases of
// flight -> vmcnt never stalls. Prologue: 12 loads, vmcnt(8). Tail: tile62
// vmcnt(6)/vmcnt(4) with h0-stages off; tile63 vmcnt(0), no stages/lookahead.

__global__ __launch_bounds__(512, 2) void gemm_bt_bias(const u16* __restrict__ A,
                                                       const u16* __restrict__ B,
                                                       const float* __restrict__ bias,
                                                       float* __restrict__ C) {
    __shared__ u16 lds[2 * LBUF];   // 128 KiB

    const int t = threadIdx.x;
    const int bm0 = blockIdx.y * BM;
    const int bn0 = blockIdx.x * BN;

    const int wave = t >> 6;
    const int lane = t & 63;
    const int wmi = wave >> 2;          // 0..1  (M wave index, 128 rows each)
    const int wni = wave & 3;           // 0..3  (N wave index, 64 cols each)
    const int lr = lane & 15;           // fragment row within 16
    const int q  = lane >> 4;           // k-quad 0..3

    // staging source pointers (pointer-bumped by BK per tile so the per-phase
    // global offsets fold into the load's immediate)
    const u16* gA[2]; const u16* gB[2];
#pragma unroll
    for (int l = 0; l < 2; ++l) {
        const int ci = l * 512 + t;
        const int ldsrow = ci >> 3;
        const int c = (ci & 7) ^ (ldsrow & 7);       // unswizzled chunk
        const int r = 2 * ldsrow + (c >> 2);         // tile row 0..255
        const int kk = (c & 3) * 8;                  // k offset within half
        gA[l] = A + (size_t)(bm0 + r) * KDIM + kk;
        gB[l] = B + (size_t)(bn0 + r) * KDIM + kk;
    }

    // fragment-read lane constants (slot is frag-index independent)
    const int aslot = (((lr & 1) << 2) + q) ^ ((lr >> 1) & 7);
    const int aLane = (wmi * 64 + (lr >> 1)) * 64 + aslot * 8;   // + i*512
    const int bLane = (wni * 32 + (lr >> 1)) * 64 + aslot * 8;   // + j*512

    floatx4 acc[8][4] = {};
    short8 afA[4], afB[4], bfA[4], bfB[4];

#define STAGE_A(CUR, H, DK) do { \
    __builtin_amdgcn_global_load_lds((gas_ptr)(gA[0] + (DK) * BK + (H) * 32), \
        (lds_ptr)(lds + (CUR) * LBUF + (H) * 8192 + t * 8), 16, 0, 0); \
    __builtin_amdgcn_global_load_lds((gas_ptr)(gA[1] + (DK) * BK + (H) * 32), \
        (lds_ptr)(lds + (CUR) * LBUF + (H) * 8192 + 4096 + t * 8), 16, 0, 0); \
} while (0)

#define STAGE_B(CUR, H, DK) do { \
    __builtin_amdgcn_global_load_lds((gas_ptr)(gB[0] + (DK) * BK + (H) * 32), \
        (lds_ptr)(lds + (CUR) * LBUF + 16384 + (H) * 8192 + t * 8), 16, 0, 0); \
    __builtin_amdgcn_global_load_lds((gas_ptr)(gB[1] + (DK) * BK + (H) * 32), \
        (lds_ptr)(lds + (CUR) * LBUF + 16384 + (H) * 8192 + 4096 + t * 8), 16, 0, 0); \
} while (0)

#define RD_AF(DST, CUR, H, I0) do { \
    const u16* _p = lds + (CUR) * LBUF + (H) * 8192 + aLane; \
    DST[0] = *(const short8*)(_p + ((I0) + 0) * 512); \
    DST[1] = *(const short8*)(_p + ((I0) + 1) * 512); \
    DST[2] = *(const short8*)(_p + ((I0) + 2) * 512); \
    DST[3] = *(const short8*)(_p + ((I0) + 3) * 512); \
} while (0)

#define RD_BF(DST, CUR, H) do { \
    const u16* _q = lds + (CUR) * LBUF + 16384 + (H) * 8192 + bLane; \
    DST[0] = *(const short8*)(_q + 0 * 512); \
    DST[1] = *(const short8*)(_q + 1 * 512); \
    DST[2] = *(const short8*)(_q + 2 * 512); \
    DST[3] = *(const short8*)(_q + 3 * 512); \
} while (0)

#define MFMA16(AF, BF, IOFF) do { \
    _Pragma("unroll") \
    for (int i2 = 0; i2 < 4; ++i2) { \
        _Pragma("unroll") \
        for (int j = 0; j < 4; ++j) \
            acc[(IOFF) + i2][j] = __builtin_amdgcn_mfma_f32_16x16x32_bf16( \
                AF[i2], BF[j], acc[(IOFF) + i2][j], 0, 0, 0); \
    } \
} while (0)

#define SCB() __builtin_amdgcn_sched_barrier(0)
#define VM8 do { SCB(); asm volatile("s_waitcnt vmcnt(8)"); SCB(); } while (0)
#define VM6 do { SCB(); asm volatile("s_waitcnt vmcnt(6)"); SCB(); } while (0)
#define VM4 do { SCB(); asm volatile("s_waitcnt vmcnt(4)"); SCB(); } while (0)
#define VM0 do { SCB(); asm volatile("s_waitcnt vmcnt(0)"); SCB(); } while (0)
#define NOVM ((void)0)
#define BAR() do { SCB(); __builtin_amdgcn_s_barrier(); SCB(); } while (0)

#define PH(RD, STG, MF, TAIL) do { \
    RD; \
    STG; \
    __builtin_amdgcn_s_setprio(1); \
    MF; \
    __builtin_amdgcn_s_setprio(0); \
    TAIL; \
    BAR(); \
} while (0)

#define KTILE(CUR, S12, S34, VM1, VM3, P4RD) do { \
    PH(RD_AF(afB, CUR, 0, 4), \
       { if (S12) STAGE_A((CUR) ^ 1, 1, 1); }, MFMA16(afA, bfA, 0), VM1); \
    PH({ RD_AF(afA, CUR, 1, 0); RD_BF(bfB, CUR, 1); }, \
       { if (S12) STAGE_B((CUR) ^ 1, 1, 1); }, MFMA16(afB, bfA, 4), NOVM); \
    PH(RD_AF(afB, CUR, 1, 4), \
       { if (S34) STAGE_A(CUR, 0, 2); }, MFMA16(afA, bfB, 0), VM3); \
    PH({ if (P4RD) { RD_AF(afA, (CUR) ^ 1, 0, 0); RD_BF(bfA, (CUR) ^ 1, 0); } }, \
       { if (S34) STAGE_B(CUR, 0, 2); }, MFMA16(afB, bfB, 4), NOVM); \
    gA[0] += BK; gA[1] += BK; gB[0] += BK; gB[1] += BK; \
} while (0)

    // ---- prologue: T0.h0, T0.h1, T1.h0 (12 loads); drain T0.h0; pre-read
    // p1's fragments (h0.m0-3 + h0.bf)
    STAGE_A(0, 0, 0); STAGE_B(0, 0, 0);
    STAGE_A(0, 1, 0); STAGE_B(0, 1, 0);
    STAGE_A(1, 0, 1); STAGE_B(1, 0, 1);
    VM8;
    BAR();
    RD_AF(afA, 0, 0, 0);
    RD_BF(bfA, 0, 0);

    // ---- main loop: tiles 0..61 ----
    for (int it = 0; it < 31; ++it) {
        KTILE(0, 1, 1, VM6, VM6, 1);
        KTILE(1, 1, 1, VM6, VM6, 1);
    }
    // ---- tail: tile 62 (stages T63.h1 only), tile 63 (stages nothing) ----
    KTILE(0, 1, 0, VM6, VM4, 1);
    KTILE(1, 0, 0, VM0, NOVM, 0);

    // ---- epilogue: C/D layout col=lane&15, row=(lane>>4)*4+qq [m89-verified]
#pragma unroll
    for (int j = 0; j < 4; ++j) {
        const int col = bn0 + wni * 64 + j * 16 + lr;
        const float bv = bias[col];
#pragma unroll
        for (int i = 0; i < 8; ++i) {
            const int row0 = bm0 + wmi * 128 + i * 16 + q * 4;
#pragma unroll
            for (int qq = 0; qq < 4; ++qq)
                C[(size_t)(row0 + qq) * NDIM + col] = acc[i][j][qq] + bv;
        }
    }

#undef STAGE_A
#undef STAGE_B
#undef RD_AF
#undef RD_BF
#undef MFMA16
#undef SCB
#undef VM8
#undef VM6
#undef VM4
#undef VM0
#undef NOVM
#undef BAR
#undef PH
#undef KTILE
}

extern "C" void kernel_launch(void* const* d_in, const int* in_sizes, int n_in,
                              void* d_out, int out_size, void* d_ws, size_t ws_size,
                              hipStream_t stream) {
    const float* x = (const float*)d_in[0];      // (4096, 4096) fp32
    const float* w = (const float*)d_in[1];      // (4096, 4096) fp32, OUT x IN
    const float* bias = (const float*)d_in[2];   // (4096,) fp32
    float* out = (float*)d_out;                  // (4096, 4096) fp32

    u16* xa = (u16*)d_ws;                        // 32 MiB bf16 x
    u16* wb = xa + (size_t)MDIM * KDIM;          // 32 MiB bf16 W

    const int blocks_per_mat = (MDIM * KDIM) / 4 / 256;   // 16384
    cvt2_f32_bf16<<<blocks_per_mat * 2, 256, 0, stream>>>(x, w, xa, wb);

    dim3 grid(NDIM / BN, MDIM / BM);             // 16 x 16
    gemm_bt_bias<<<grid, dim3(512), 0, stream>>>(xa, wb, bias, out);
}